// Round 3
// 279.672 us; speedup vs baseline: 1.0593x; 1.0593x over previous
//
#include <hip/hip_runtime.h>

#define B_SZ   256
#define S_SZ   4096
#define H_SZ   64
#define NCHUNK 32
#define CHUNK  (S_SZ / NCHUNK)      // 128
#define NWAVE  4                    // waves per block (256 threads — proven size)
#define CPW    (NCHUNK / NWAVE)     // chunks per wave = 8

#define INV2PI   0.15915494309189535f
#define TWOPI_HI 6.2831854820251465f       // float(2*pi)
#define TWOPI_LO (-1.7484556000744887e-7f) // 2*pi - TWOPI_HI (into fp32)

// One block per batch row b. 4 waves; lane = h.
// Phase 1: per-chunk raw delta sums -> lds_part (replaces the ws global
//          round-trip and the second kernel of the two-pass version).
// Phase 2: per-wave scan of its 8 chunks; Hseq written via a per-wave LDS
//          4x64 transpose so every wave store is a contiguous 1 KB dwordx4.
__global__ __launch_bounds__(256, 2) void k_fused(
    const float* __restrict__ x, const float* __restrict__ W_e,
    const float* __restrict__ b_e, const float* __restrict__ omega,
    const float* __restrict__ W_r, const float* __restrict__ b_r,
    float* __restrict__ out, float* __restrict__ hseq)
{
    __shared__ float lds_x[S_SZ];                 // 16 KB: whole x row
    __shared__ float lds_part[NCHUNK * H_SZ];     //  8 KB: chunk partials
    __shared__ float lds_t[NWAVE * 4 * H_SZ];     //  4 KB: per-wave transpose

    const int b    = blockIdx.x;
    const int tid  = threadIdx.x;
    const int w    = tid >> 6;
    const int lane = tid & 63;                    // lane = h

    // stage x row, coalesced: 256 threads x float4 x 4 iters = 16 KB
    {
        const float4* xg = (const float4*)(x + (size_t)b * S_SZ);
        float4* xl = (float4*)lds_x;
        #pragma unroll
        for (int k = 0; k < 4; ++k)
            xl[tid + k * 256] = xg[tid + k * 256];
    }

    const float we = W_e[lane];
    const float be = b_e[lane];
    const float om = omega[lane];

    __syncthreads();

    // ---- phase 1: per-chunk raw delta sums ----
    // sum(delta) = we*sum(x) + CHUNK*be - 2pi*sum(n), n = rint(p/2pi)
    // (same rounding expression as phase 2 -> identical wrap picks)
    for (int cc = 0; cc < CPW; ++cc) {
        const int c = w * CPW + cc;
        const float4* xl = (const float4*)(lds_x + c * CHUNK);  // broadcast reads
        float accN = 0.f;   // wrap integers: exact in fp32, order-independent
        float accX = 0.f;
        #pragma unroll 4
        for (int q = 0; q < CHUNK / 4; ++q) {
            float4 xv = xl[q];
            { float p = fmaf(xv.x, we, be); accN += rintf(p * INV2PI); accX += xv.x; }
            { float p = fmaf(xv.y, we, be); accN += rintf(p * INV2PI); accX += xv.y; }
            { float p = fmaf(xv.z, we, be); accN += rintf(p * INV2PI); accX += xv.z; }
            { float p = fmaf(xv.w, we, be); accN += rintf(p * INV2PI); accX += xv.w; }
        }
        float sP = fmaf(we, accX, (float)CHUNK * be);
        float d  = fmaf(accN, -TWOPI_HI, sP);
        d        = fmaf(accN, -TWOPI_LO, d);
        lds_part[c * H_SZ + lane] = d;
    }

    __syncthreads();

    // ---- phase 2: scan + wide stores ----
    // exclusive prefix of chunk sums for this wave's first chunk (LDS, cheap);
    // same left-to-right association as the verified two-pass version.
    float base = 0.f;
    for (int c = 0; c < w * CPW; ++c)           // wave-uniform trip count
        base += lds_part[c * H_SZ + lane];

    float* tbuf = lds_t + w * (4 * H_SZ);       // private 1 KB per wave
    float Hval = 0.f;

    for (int cc = 0; cc < CPW; ++cc) {
        const int c = w * CPW + cc;
        const float4* xl = (const float4*)(lds_x + c * CHUNK);
        float4* gq = (float4*)(hseq + ((size_t)b * S_SZ + c * CHUNK) * H_SZ);
        const float obase = om * base;
        float acc = 0.f;

        #pragma unroll 2
        for (int q = 0; q < CHUNK / 4; ++q) {
            float4 xv = xl[q];
            {
                float p = fmaf(xv.x, we, be); float n = rintf(p * INV2PI);
                float d0 = fmaf(n, -TWOPI_HI, p); d0 = fmaf(n, -TWOPI_LO, d0);
                acc += d0; Hval = fmaf(om, acc, obase);
                tbuf[0 * H_SZ + lane] = Hval;
            }
            {
                float p = fmaf(xv.y, we, be); float n = rintf(p * INV2PI);
                float d0 = fmaf(n, -TWOPI_HI, p); d0 = fmaf(n, -TWOPI_LO, d0);
                acc += d0; Hval = fmaf(om, acc, obase);
                tbuf[1 * H_SZ + lane] = Hval;
            }
            {
                float p = fmaf(xv.z, we, be); float n = rintf(p * INV2PI);
                float d0 = fmaf(n, -TWOPI_HI, p); d0 = fmaf(n, -TWOPI_LO, d0);
                acc += d0; Hval = fmaf(om, acc, obase);
                tbuf[2 * H_SZ + lane] = Hval;
            }
            {
                float p = fmaf(xv.w, we, be); float n = rintf(p * INV2PI);
                float d0 = fmaf(n, -TWOPI_HI, p); d0 = fmaf(n, -TWOPI_LO, d0);
                acc += d0; Hval = fmaf(om, acc, obase);
                tbuf[3 * H_SZ + lane] = Hval;
            }
            // transpose read: lane l -> row s0+(l>>4), cols (l&15)*4..+3
            float4 v = ((const float4*)tbuf)[lane];
            // wave covers [s0..s0+3] x [0..63]: contiguous 1 KB store
            gq[q * 64 + lane] = v;
        }

        // advance base by the phase-1 chunk sum (same association as 2-pass)
        base += lds_part[c * H_SZ + lane];
    }

    // epilogue: wave owning chunk 31 holds H at s = S-1 in Hval (lane = h)
    if (w == NWAVE - 1) {
        float ph = Hval;
        float v = cosf(ph) * W_r[lane]
                + sinf(ph) * W_r[H_SZ + lane]
                + ph       * W_r[2 * H_SZ + lane];
        #pragma unroll
        for (int off = 32; off > 0; off >>= 1)
            v += __shfl_down(v, off, 64);
        if (lane == 0) out[b] = v + b_r[0];
    }
}

extern "C" void kernel_launch(void* const* d_in, const int* in_sizes, int n_in,
                              void* d_out, int out_size, void* d_ws, size_t ws_size,
                              hipStream_t stream) {
    const float* x     = (const float*)d_in[0];
    const float* W_e   = (const float*)d_in[1];
    const float* b_e   = (const float*)d_in[2];
    const float* omega = (const float*)d_in[3];
    const float* W_r   = (const float*)d_in[4];
    const float* b_r   = (const float*)d_in[5];

    float* out  = (float*)d_out;          // (B,1) = 256 floats first
    float* hseq = out + B_SZ;             // then (B,S,H)

    k_fused<<<dim3(B_SZ), dim3(256), 0, stream>>>(
        x, W_e, b_e, omega, W_r, b_r, out, hseq);
}

// Round 4
// 279.520 us; speedup vs baseline: 1.0599x; 1.0005x over previous
//
#include <hip/hip_runtime.h>

#define B_SZ   256
#define S_SZ   4096
#define H_SZ   64
#define NCHUNK 32
#define CHUNK  (S_SZ / NCHUNK)      // 128
#define NWAVE  4                    // waves per block (256 threads)
#define RPB    4                    // row-splits: blocks per batch row
#define CPB    (NCHUNK / RPB)       // chunks per block in phase 2 = 8
#define CPW2   (CPB / NWAVE)        // chunks per wave in phase 2 = 2

#define INV2PI   0.15915494309189535f
#define TWOPI_HI 6.2831854820251465f       // float(2*pi)
#define TWOPI_LO (-1.7484556000744887e-7f) // 2*pi - TWOPI_HI (into fp32)

// 4 blocks per batch row (grid 1024 = 4 blocks/CU, 16 waves/CU) to give the
// store path TLP. Block r redundantly computes phase-1 chunk sums for chunks
// [0, (r+1)*CPB) with the exact same per-chunk expression as before, so the
// left-to-right prefix association (and absmax) is bit-identical to the
// verified single-block version. Phase 2: each wave scans 2 chunks and
// writes Hseq via a per-wave 4x64 LDS transpose -> contiguous 1 KB dwordx4.
__global__ __launch_bounds__(256, 4) void k_fused(
    const float* __restrict__ x, const float* __restrict__ W_e,
    const float* __restrict__ b_e, const float* __restrict__ omega,
    const float* __restrict__ W_r, const float* __restrict__ b_r,
    float* __restrict__ out, float* __restrict__ hseq)
{
    __shared__ float lds_x[S_SZ];                 // 16 KB: whole x row
    __shared__ float lds_part[NCHUNK * H_SZ];     //  8 KB: chunk partials
    __shared__ float lds_t[NWAVE * 4 * H_SZ];     //  4 KB: per-wave transpose

    const int b    = blockIdx.x >> 2;             // blockIdx / RPB
    const int r    = blockIdx.x & (RPB - 1);
    const int tid  = threadIdx.x;
    const int w    = tid >> 6;
    const int lane = tid & 63;                    // lane = h

    // stage x row, coalesced: 256 threads x float4 x 4 iters = 16 KB
    {
        const float4* xg = (const float4*)(x + (size_t)b * S_SZ);
        float4* xl = (float4*)lds_x;
        #pragma unroll
        for (int k = 0; k < 4; ++k)
            xl[tid + k * 256] = xg[tid + k * 256];
    }

    const float we = W_e[lane];
    const float be = b_e[lane];
    const float om = omega[lane];

    __syncthreads();

    // ---- phase 1: per-chunk raw delta sums for chunks [0, cNeed) ----
    // sum(delta) = we*sum(x) + CHUNK*be - 2pi*sum(n), n = rint(p/2pi)
    // (same per-chunk expression as phase 2 -> identical wrap picks;
    //  identical bits to the single-block version regardless of which
    //  wave/block computes a given chunk)
    const int cNeed = (r + 1) * CPB;              // 8,16,24,32
    for (int c = w; c < cNeed; c += NWAVE) {
        const float4* xl = (const float4*)(lds_x + c * CHUNK);  // broadcast reads
        float accN = 0.f;   // wrap integers: exact in fp32, order-independent
        float accX = 0.f;
        #pragma unroll 4
        for (int q = 0; q < CHUNK / 4; ++q) {
            float4 xv = xl[q];
            { float p = fmaf(xv.x, we, be); accN += rintf(p * INV2PI); accX += xv.x; }
            { float p = fmaf(xv.y, we, be); accN += rintf(p * INV2PI); accX += xv.y; }
            { float p = fmaf(xv.z, we, be); accN += rintf(p * INV2PI); accX += xv.z; }
            { float p = fmaf(xv.w, we, be); accN += rintf(p * INV2PI); accX += xv.w; }
        }
        float sP = fmaf(we, accX, (float)CHUNK * be);
        float d  = fmaf(accN, -TWOPI_HI, sP);
        d        = fmaf(accN, -TWOPI_LO, d);
        lds_part[c * H_SZ + lane] = d;
    }

    __syncthreads();

    // ---- phase 2: scan + wide stores for this block's 8 chunks ----
    // exclusive prefix of chunk sums, left-to-right (same association as the
    // verified version)
    const int cFirst = r * CPB + w * CPW2;
    float base = 0.f;
    for (int c = 0; c < cFirst; ++c)              // wave-uniform trip count
        base += lds_part[c * H_SZ + lane];

    float* tbuf = lds_t + w * (4 * H_SZ);         // private 1 KB per wave
    float Hval = 0.f;

    for (int cc = 0; cc < CPW2; ++cc) {
        const int c = cFirst + cc;
        const float4* xl = (const float4*)(lds_x + c * CHUNK);
        float4* gq = (float4*)(hseq + ((size_t)b * S_SZ + c * CHUNK) * H_SZ);
        const float obase = om * base;
        float acc = 0.f;

        #pragma unroll 2
        for (int q = 0; q < CHUNK / 4; ++q) {
            float4 xv = xl[q];
            {
                float p = fmaf(xv.x, we, be); float n = rintf(p * INV2PI);
                float d0 = fmaf(n, -TWOPI_HI, p); d0 = fmaf(n, -TWOPI_LO, d0);
                acc += d0; Hval = fmaf(om, acc, obase);
                tbuf[0 * H_SZ + lane] = Hval;
            }
            {
                float p = fmaf(xv.y, we, be); float n = rintf(p * INV2PI);
                float d0 = fmaf(n, -TWOPI_HI, p); d0 = fmaf(n, -TWOPI_LO, d0);
                acc += d0; Hval = fmaf(om, acc, obase);
                tbuf[1 * H_SZ + lane] = Hval;
            }
            {
                float p = fmaf(xv.z, we, be); float n = rintf(p * INV2PI);
                float d0 = fmaf(n, -TWOPI_HI, p); d0 = fmaf(n, -TWOPI_LO, d0);
                acc += d0; Hval = fmaf(om, acc, obase);
                tbuf[2 * H_SZ + lane] = Hval;
            }
            {
                float p = fmaf(xv.w, we, be); float n = rintf(p * INV2PI);
                float d0 = fmaf(n, -TWOPI_HI, p); d0 = fmaf(n, -TWOPI_LO, d0);
                acc += d0; Hval = fmaf(om, acc, obase);
                tbuf[3 * H_SZ + lane] = Hval;
            }
            // transpose read: lane l -> row s0+(l>>4), cols (l&15)*4..+3
            float4 v = ((const float4*)tbuf)[lane];
            // wave covers [s0..s0+3] x [0..63]: contiguous 1 KB store
            gq[q * 64 + lane] = v;
        }

        // advance base by the phase-1 chunk sum (same association as before)
        base += lds_part[c * H_SZ + lane];
    }

    // epilogue: block r=3, wave 3 owns chunk 31; Hval = H at s = S-1, h = lane
    if (r == RPB - 1 && w == NWAVE - 1) {
        float ph = Hval;
        float v = cosf(ph) * W_r[lane]
                + sinf(ph) * W_r[H_SZ + lane]
                + ph       * W_r[2 * H_SZ + lane];
        #pragma unroll
        for (int off = 32; off > 0; off >>= 1)
            v += __shfl_down(v, off, 64);
        if (lane == 0) out[b] = v + b_r[0];
    }
}

extern "C" void kernel_launch(void* const* d_in, const int* in_sizes, int n_in,
                              void* d_out, int out_size, void* d_ws, size_t ws_size,
                              hipStream_t stream) {
    const float* x     = (const float*)d_in[0];
    const float* W_e   = (const float*)d_in[1];
    const float* b_e   = (const float*)d_in[2];
    const float* omega = (const float*)d_in[3];
    const float* W_r   = (const float*)d_in[4];
    const float* b_r   = (const float*)d_in[5];

    float* out  = (float*)d_out;          // (B,1) = 256 floats first
    float* hseq = out + B_SZ;             // then (B,S,H)

    k_fused<<<dim3(B_SZ * RPB), dim3(256), 0, stream>>>(
        x, W_e, b_e, omega, W_r, b_r, out, hseq);
}